// Round 7
// baseline (373.183 us; speedup 1.0000x reference)
//
#include <hip/hip_runtime.h>
#include <math.h>

// Problem constants
#define BB   16
#define TT   4
#define CC   2048
#define NH   16
#define NKV  4
#define DH   128
#define GRP  4
#define SCACHE 4096
#define SATT 2052          // sink(4) + window(2048)
#define CS   128           // keys per attention chunk (32 per wave)
#define NCH  17            // ceil(2052/128)
#define KSPL 32            // K-split for QKV GEMM (slice = 64)
#define KSPL_P 16          // K-split for proj GEMM (slice = 128)

typedef unsigned int  uint32;
typedef unsigned short ushort_t;
typedef __attribute__((ext_vector_type(8))) __bf16 bf16x8;
typedef __attribute__((ext_vector_type(4))) float  f32x4;

__device__ __forceinline__ uint32 f2bf_bits(float f) {
    uint32 u = __float_as_uint(f);
    return (u + 0x7FFFu + ((u >> 16) & 1u)) >> 16;   // RN-even
}
__device__ __forceinline__ uint32 pk2(float lo, float hi) {
    return f2bf_bits(lo) | (f2bf_bits(hi) << 16);
}
// static-index float4 component (folds under #pragma unroll)
#define F4C(v, j) ((j)==0 ? (v).x : (j)==1 ? (v).y : (j)==2 ? (v).z : (v).w)

// ---- Workspace layout (bytes) ----
// scr region: first 0.75 MB = QKV atomic accumulator [64][3072] f32 (memset 0),
// then reused by k_attn for 9.2 MB of attention partials. Total << d_ws (512 MiB).
#define Q_OFF    0
#define KNEW_OFF 524288
#define VNEW_OFF 655360
#define Y_OFF    786432
#define SCR_OFF  1310720

// -------- Kernel 1: QKV GEMM, KSPL=32, atomicAdd into L2-hot accumulator -------
// grid (48, 32): x = col-tile of 64, y = k-slice of 64. Weights read once.
// Output: qkv_acc[64][3072], pre-zeroed by hipMemsetAsync.
__global__ __launch_bounds__(256) void k_qkv(
    const float* __restrict__ x, const float* __restrict__ wq,
    const float* __restrict__ wk, const float* __restrict__ wv,
    float* __restrict__ qkv_acc)
{
    __shared__ float xs[64][64];           // 16 KB
    int ns = blockIdx.x, ks = blockIdx.y;
    int tid = threadIdx.x;
    int k0 = ks * 64;

    #pragma unroll
    for (int it = 0; it < 4; ++it) {
        int slot = it * 256 + tid;          // 1024 float4 slots
        int row = slot >> 4, c4 = slot & 15;
        *(float4*)&xs[row][c4 * 4] = *(const float4*)(x + (size_t)row * CC + k0 + c4 * 4);
    }
    __syncthreads();

    int cp = tid & 31, rg = tid >> 5;       // col pair, row group of 8
    const float* wp; int ldw, col;
    if (ns < 32)      { ldw = 2048; col = ns * 64 + cp * 2;
                        wp = wq + (size_t)k0 * 2048 + ns * 64 + cp * 2; }
    else if (ns < 40) { ldw = 512;  col = 2048 + (ns - 32) * 64 + cp * 2;
                        wp = wk + (size_t)k0 * 512 + (ns - 32) * 64 + cp * 2; }
    else              { ldw = 512;  col = 2560 + (ns - 40) * 64 + cp * 2;
                        wp = wv + (size_t)k0 * 512 + (ns - 40) * 64 + cp * 2; }

    float a[16];
    #pragma unroll
    for (int i = 0; i < 16; ++i) a[i] = 0.f;

    for (int k = 0; k < 64; k += 4) {
        float2 w0 = *(const float2*)(wp);
        float2 w1 = *(const float2*)(wp + ldw);
        float2 w2 = *(const float2*)(wp + 2 * ldw);
        float2 w3 = *(const float2*)(wp + 3 * ldw);
        wp += 4 * ldw;
        #pragma unroll
        for (int m = 0; m < 8; ++m) {
            float4 xv = *(const float4*)&xs[rg * 8 + m][k];
            float s0 = a[2*m], s1 = a[2*m+1];
            s0 = fmaf(xv.x, w0.x, s0); s1 = fmaf(xv.x, w0.y, s1);
            s0 = fmaf(xv.y, w1.x, s0); s1 = fmaf(xv.y, w1.y, s1);
            s0 = fmaf(xv.z, w2.x, s0); s1 = fmaf(xv.z, w2.y, s1);
            s0 = fmaf(xv.w, w3.x, s0); s1 = fmaf(xv.w, w3.y, s1);
            a[2*m] = s0; a[2*m+1] = s1;
        }
    }
    #pragma unroll
    for (int m = 0; m < 8; ++m) {
        float* dst = qkv_acc + (size_t)(rg * 8 + m) * 3072 + col;
        atomicAdd(dst,     a[2*m]);
        atomicAdd(dst + 1, a[2*m+1]);
    }
}

// -------- Kernel 2: RoPE from accumulated QKV (single 0.75 MB L2-hot read) -----
__global__ __launch_bounds__(256) void k_fix(
    const float* __restrict__ qkv_acc, const int* __restrict__ spp,
    float* __restrict__ qws, float* __restrict__ knew, float* __restrict__ vnew)
{
    int u = blockIdx.x * 256 + threadIdx.x;
    int m = blockIdx.y;
    int b = m >> 2, t = m & 3;
    int sp = spp[0];
    const float NEG_L2_10K_64 = -0.20762050593048633f;
    const float* p = qkv_acc + (size_t)m * 3072;

    if (u < 1024) {
        int h = u >> 6, d = u & 63;
        int col = h * 128 + d;
        float s1 = p[col], s2 = p[col + 64];
        float inv = exp2f((float)d * NEG_L2_10K_64);
        float ang = (float)(sp + t) * inv;
        float cc = cosf(ang), ss = sinf(ang);
        float* dst = qws + (size_t)((b * NH + h) * TT + t) * DH + d;
        dst[0]  = s1 * cc - s2 * ss;
        dst[64] = s1 * ss + s2 * cc;
    } else if (u < 1280) {
        int v = u - 1024;
        int kv = v >> 6, d = v & 63;
        int col = 2048 + kv * 128 + d;
        float s1 = p[col], s2 = p[col + 64];
        float inv = exp2f((float)d * NEG_L2_10K_64);
        float ang = (float)(sp + t) * inv;
        float cc = cosf(ang), ss = sinf(ang);
        float* dst = knew + (size_t)((b * NKV + kv) * TT + t) * DH + d;
        dst[0]  = s1 * cc - s2 * ss;
        dst[64] = s1 * ss + s2 * cc;
    } else {
        int v = u - 1280;
        int c0 = v * 2;
        int kv = c0 >> 7, dd = c0 & 127;
        float s1 = p[2560 + c0], s2 = p[2560 + c0 + 1];
        float* dst = vnew + (size_t)((b * NKV + kv) * TT + t) * DH + dd;
        dst[0] = s1; dst[1] = s2;
    }
}

// key/value row j in [0, 2052)
__device__ __forceinline__ const float* kv_row(
    const float* cache, const float* newt, int bk, int j)
{
    if (j < 4)         return cache + ((size_t)bk * SCACHE + j) * DH;
    else if (j < 2048) return cache + ((size_t)bk * SCACHE + j + 2048) * DH;
    else               return newt  + ((size_t)(bk * TT + (j - 2048))) * DH;
}

// -------- Kernel 3: MFMA flash-decode attention partials -----------------------
// CS=128, 1088 blocks = 4.25 blk/CU. Per-wave independent 32-key sub-chunks:
// K->reg->frag, V->wave-private-LDS transpose (lgkmcnt only), in-register
// softmax via 16-lane shfl_xor, PV k=32. Waves meet only at the 2-barrier
// tail merge. NEW: s_setprio(1) around MFMA clusters (T5 — independent wave
// chains = the regime where setprio pays, per m191).
// Verified layouts: A[m=lane&15][k=quad*8+j], B[k=quad*8+j][n=lane&15],
// C/D[row=quad*4+reg][col=lane&15].
__global__ __launch_bounds__(256) void k_attn(
    const float* __restrict__ qws,
    const float* __restrict__ kc, const float* __restrict__ vc,
    const float* __restrict__ knew, const float* __restrict__ vnew,
    float* __restrict__ part)
{
    // words: [0,8192) vt (4 waves x 2048w) -- phase2: o_all [4][16][132] f32 (8448w)
    //        [8448,9472) pl (4 waves x 256w = [16][32] u16 each)
    //        [9472,9536) red_m[4][16]  [9536,9600) red_l[4][16]
    __shared__ __align__(16) uint32 smem[9600];   // 38400 B

    int bx = blockIdx.x;
    int c  = bx % NCH;
    int bk = bx / NCH;
    int b  = bk >> 2, kvh = bk & 3;
    int j0 = c * CS;
    int jn = (SATT - j0 < CS) ? (SATT - j0) : CS;
    int tid  = threadIdx.x;
    int w    = tid >> 6, lane = tid & 63;
    int quad = lane >> 4, l15 = lane & 15;
    const float scale = 0.08838834764831845f;   // 1/sqrt(128), folded into Q

    uint32*   vt    = smem + w * 2048;                       // [128 d][16 u32] swz
    ushort_t* pl    = (ushort_t*)(smem + 8448) + w * 512;    // [16 r][32 k] u16 swz
    float*    red_m = (float*)(smem + 9472);
    float*    red_l = red_m + 64;
    float*    o_all = (float*)smem;                          // [4][16][132] (phase 2)

    int base = w * 32;                      // wave's first local key

    // ---- K rows (base+l15, base+16+l15), clamped; 128 d each ----
    int rA = base + l15, rB = base + 16 + l15;
    const float* kAp = kv_row(kc, knew, bk, j0 + (rA < jn ? rA : 0));
    const float* kBp = kv_row(kc, knew, bk, j0 + (rB < jn ? rB : 0));
    float4 ka[8], kb[8];
    #pragma unroll
    for (int ks = 0; ks < 4; ++ks) {
        ka[2*ks]   = *(const float4*)(kAp + ks * 32 + quad * 8);
        ka[2*ks+1] = *(const float4*)(kAp + ks * 32 + quad * 8 + 4);
        kb[2*ks]   = *(const float4*)(kBp + ks * 32 + quad * 8);
        kb[2*ks+1] = *(const float4*)(kBp + ks * 32 + quad * 8 + 4);
    }

    // ---- V burst 1: lane = (pair p=l15, d-quarter dq=quad), d [dq*32, +16) ----
    int key0 = base + 2 * l15, key1 = key0 + 1;
    bool okA = key0 < jn, okB = key1 < jn;
    const float* rva = kv_row(vc, vnew, bk, j0 + (okA ? key0 : 0));
    const float* rvb = kv_row(vc, vnew, bk, j0 + (okB ? key1 : 0));
    float4 va[4], vb[4];
    #pragma unroll
    for (int i = 0; i < 4; ++i) {
        va[i] = *(const float4*)(rva + quad * 32 + i * 4);
        vb[i] = *(const float4*)(rvb + quad * 32 + i * 4);
    }

    // ---- Q fragments, scale folded (L2-hot) ----
    bf16x8 aq[4];
    {
        int h = kvh * GRP + (l15 >> 2), t = l15 & 3;
        const float* qr = qws + (size_t)((b * NH + h) * TT + t) * DH;
        #pragma unroll
        for (int ks = 0; ks < 4; ++ks) {
            float4 f0 = *(const float4*)(qr + ks * 32 + quad * 8);
            float4 f1 = *(const float4*)(qr + ks * 32 + quad * 8 + 4);
            union { uint32 u[4]; bf16x8 v; } pk_;
            pk_.u[0] = pk2(f0.x * scale, f0.y * scale);
            pk_.u[1] = pk2(f0.z * scale, f0.w * scale);
            pk_.u[2] = pk2(f1.x * scale, f1.y * scale);
            pk_.u[3] = pk2(f1.z * scale, f1.w * scale);
            aq[ks] = pk_.v;
        }
    }

    // ---- QK^T: 8 MFMAs (2 key-tiles x 4 ks) ----
    f32x4 s0 = {0.f, 0.f, 0.f, 0.f}, s1 = {0.f, 0.f, 0.f, 0.f};
    __builtin_amdgcn_s_setprio(1);
    #pragma unroll
    for (int ks = 0; ks < 4; ++ks) {
        union { uint32 u[4]; bf16x8 v; } pa, pb;
        pa.u[0] = pk2(ka[2*ks].x,   ka[2*ks].y);
        pa.u[1] = pk2(ka[2*ks].z,   ka[2*ks].w);
        pa.u[2] = pk2(ka[2*ks+1].x, ka[2*ks+1].y);
        pa.u[3] = pk2(ka[2*ks+1].z, ka[2*ks+1].w);
        pb.u[0] = pk2(kb[2*ks].x,   kb[2*ks].y);
        pb.u[1] = pk2(kb[2*ks].z,   kb[2*ks].w);
        pb.u[2] = pk2(kb[2*ks+1].x, kb[2*ks+1].y);
        pb.u[3] = pk2(kb[2*ks+1].z, kb[2*ks+1].w);
        s0 = __builtin_amdgcn_mfma_f32_16x16x32_bf16(aq[ks], pa.v, s0, 0, 0, 0);
        s1 = __builtin_amdgcn_mfma_f32_16x16x32_bf16(aq[ks], pb.v, s1, 0, 0, 0);
    }
    __builtin_amdgcn_s_setprio(0);

    // ---- stage V burst1 -> vt (swizzled); issue burst2 ----
    #pragma unroll
    for (int i = 0; i < 4; ++i) {
        #pragma unroll
        for (int jj = 0; jj < 4; ++jj) {
            int dd = i * 4 + jj;                       // 0..15 (compile-time)
            int d  = quad * 32 + dd;
            int sw = (dd ^ (dd >> 2)) & 3;             // compile-time
            float fa = okA ? F4C(va[i], jj) : 0.f;
            float fb = okB ? F4C(vb[i], jj) : 0.f;
            vt[d * 16 + ((((l15 >> 2) ^ sw) << 2) | (l15 & 3))] = pk2(fa, fb);
        }
    }
    float4 va2[4], vb2[4];
    #pragma unroll
    for (int i = 0; i < 4; ++i) {
        va2[i] = *(const float4*)(rva + quad * 32 + 16 + i * 4);
        vb2[i] = *(const float4*)(rvb + quad * 32 + 16 + i * 4);
    }

    // ---- per-wave softmax over its 32 keys (no cross-wave traffic) ----
    bool c0ok = (base + l15) < jn, c1ok = (base + 16 + l15) < jn;
    float sc0[4], sc1[4], mloc[4];
    #pragma unroll
    for (int i = 0; i < 4; ++i) {
        sc0[i] = c0ok ? s0[i] : -1e30f;
        sc1[i] = c1ok ? s1[i] : -1e30f;
        float v = fmaxf(sc0[i], sc1[i]);
        v = fmaxf(v, __shfl_xor(v, 1));
        v = fmaxf(v, __shfl_xor(v, 2));
        v = fmaxf(v, __shfl_xor(v, 4));
        v = fmaxf(v, __shfl_xor(v, 8));
        mloc[i] = v;
        float p0 = __expf(sc0[i] - v);     // all-masked wave: exp(0)=1, killed later
        float p1 = __expf(sc1[i] - v);
        int r   = quad * 4 + i;
        int swr = (i ^ quad) & 3;          // (r ^ (r>>2)) & 3
        pl[r * 32 + ((((l15 >> 3)    ) ^ swr) << 3) + (l15 & 7)] = (ushort_t)f2bf_bits(p0);
        pl[r * 32 + ((((l15 >> 3) | 2) ^ swr) << 3) + (l15 & 7)] = (ushort_t)f2bf_bits(p1);
        float su = p0 + p1;
        su += __shfl_xor(su, 1);
        su += __shfl_xor(su, 2);
        su += __shfl_xor(su, 4);
        su += __shfl_xor(su, 8);
        if (l15 == 0) { red_m[w * 16 + r] = v; red_l[w * 16 + r] = su; }
    }

    // ---- stage V burst2 ----
    #pragma unroll
    for (int i = 0; i < 4; ++i) {
        #pragma unroll
        for (int jj = 0; jj < 4; ++jj) {
            int dd = 16 + i * 4 + jj;                  // 16..31 (compile-time)
            int d  = quad * 32 + dd;
            int sw = (dd ^ (dd >> 2)) & 3;
            float fa = okA ? F4C(va2[i], jj) : 0.f;
            float fb = okB ? F4C(vb2[i], jj) : 0.f;
            vt[d * 16 + ((((l15 >> 2) ^ sw) << 2) | (l15 & 3))] = pk2(fa, fb);
        }
    }

    // ---- PV: one k=32 MFMA per 16-d tile (8 total); wave-private LDS reads ----
    int swp = (l15 ^ (l15 >> 2)) & 3;
    bf16x8 ap = *(const bf16x8*)&pl[l15 * 32 + ((quad ^ swp) << 3)];
    f32x4 o[8];
    #pragma unroll
    for (int t = 0; t < 8; ++t) o[t] = (f32x4){0.f, 0.f, 0.f, 0.f};
    __builtin_amdgcn_s_setprio(1);
    #pragma unroll
    for (int t = 0; t < 8; ++t) {
        int d   = t * 16 + l15;
        int swv = (d ^ (d >> 2)) & 3;
        bf16x8 bv = *(const bf16x8*)&vt[d * 16 + ((quad ^ swv) << 2)];
        o[t] = __builtin_amdgcn_mfma_f32_16x16x32_bf16(ap, bv, o[t], 0, 0, 0);
    }
    __builtin_amdgcn_s_setprio(0);

    // ---- tail merge: rescale to block max, sum 4 waves in LDS ----
    __syncthreads();    // all PV LDS reads + red_m/red_l writes done
    #pragma unroll
    for (int i = 0; i < 4; ++i) {
        int r = quad * 4 + i;
        float Mb = fmaxf(fmaxf(red_m[r], red_m[16 + r]),
                         fmaxf(red_m[32 + r], red_m[48 + r]));
        float scl = __expf(mloc[i] - Mb);   // fully-masked wave -> 0
        #pragma unroll
        for (int t = 0; t < 8; ++t)
            o_all[(w * 16 + r) * 132 + t * 16 + l15] = o[t][i] * scl;
    }
    __syncthreads();
    {
        int r = tid >> 4, dg = tid & 15;    // 16 rows x 16 d-groups of 8
        float acc[8];
        #pragma unroll
        for (int jj = 0; jj < 8; ++jj) acc[jj] = 0.f;
        #pragma unroll
        for (int ww = 0; ww < 4; ++ww) {
            const float* src = &o_all[(ww * 16 + r) * 132 + dg * 8];
            #pragma unroll
            for (int jj = 0; jj < 8; ++jj) acc[jj] += src[jj];
        }
        float* dstb = part + (size_t)(bk * NCH + c) * 16 * 132;
        #pragma unroll
        for (int jj = 0; jj < 8; ++jj) dstb[r * 132 + 4 + dg * 8 + jj] = acc[jj];
        if (dg == 0) {
            float Mb = fmaxf(fmaxf(red_m[r], red_m[16 + r]),
                             fmaxf(red_m[32 + r], red_m[48 + r]));
            float L = 0.f;
            #pragma unroll
            for (int ww = 0; ww < 4; ++ww)
                L += __expf(red_m[ww * 16 + r] - Mb) * red_l[ww * 16 + r];
            dstb[r * 132 + 0] = Mb;
            dstb[r * 132 + 1] = L;
        }
    }
}

// -------- Kernel 4: combine chunk partials -> yws; zero proj accumulator -------
__global__ __launch_bounds__(128) void k_comb(
    const float* __restrict__ part, float* __restrict__ yws,
    float* __restrict__ out)
{
    int bx = blockIdx.x;
    // zero the projection output accumulator (1024 blk x 128 thr = 131072 = 64*2048)
    out[(size_t)bx * 128 + threadIdx.x] = 0.f;

    int t = bx & 3, h = (bx >> 2) & 15, b = bx >> 6;
    int bk = b * NKV + (h >> 2);
    int r  = (h & 3) * 4 + t;
    int d  = threadIdx.x;
    float M = -1e30f;
    for (int c = 0; c < NCH; ++c)
        M = fmaxf(M, part[((size_t)(bk * NCH + c) * 16 + r) * 132]);
    float L = 0.f, y = 0.f;
    for (int c = 0; c < NCH; ++c) {
        const float* pp = part + ((size_t)(bk * NCH + c) * 16 + r) * 132;
        float w = __expf(pp[0] - M);
        L += w * pp[1];
        y  = fmaf(w, pp[4 + d], y);
    }
    yws[(size_t)(b * TT + t) * CC + h * DH + d] = y / L;
}

// -------- Kernel 5: output projection GEMM, KSPL_P=16, atomicAdd into out ------
// grid (32, 16): x = col-tile of 64, y = k-slice of 128.
__global__ __launch_bounds__(256) void k_proj(
    const float* __restrict__ yws, const float* __restrict__ wp,
    float* __restrict__ out)
{
    __shared__ float xs[64][128];          // 32 KB
    int ns = blockIdx.x, ks = blockIdx.y;
    int tid = threadIdx.x;
    int k0 = ks * 128;
    #pragma unroll
    for (int it = 0; it < 8; ++it) {
        int slot = it * 256 + tid;          // 2048 float4 slots
        int row = slot >> 5, c4 = slot & 31;
        *(float4*)&xs[row][c4 * 4] = *(const float4*)(yws + (size_t)row * CC + k0 + c4 * 4);
    }
    __syncthreads();

    int cp = tid & 31, rg = tid >> 5;
    int n = ns * 64 + cp * 2;
    const float* w = wp + (size_t)k0 * CC + n;
    float a[16];
    #pragma unroll
    for (int i = 0; i < 16; ++i) a[i] = 0.f;

    for (int k = 0; k < 128; k += 4) {
        float2 w0 = *(const float2*)(w);
        float2 w1 = *(const float2*)(w + CC);
        float2 w2 = *(const float2*)(w + 2 * CC);
        float2 w3 = *(const float2*)(w + 3 * CC);
        w += 4 * CC;
        #pragma unroll
        for (int m = 0; m < 8; ++m) {
            float4 xv = *(const float4*)&xs[rg * 8 + m][k];
            float s0 = a[2*m], s1 = a[2*m+1];
            s0 = fmaf(xv.x, w0.x, s0); s1 = fmaf(xv.x, w0.y, s1);
            s0 = fmaf(xv.y, w1.x, s0); s1 = fmaf(xv.y, w1.y, s1);
            s0 = fmaf(xv.z, w2.x, s0); s1 = fmaf(xv.z, w2.y, s1);
            s0 = fmaf(xv.w, w3.x, s0); s1 = fmaf(xv.w, w3.y, s1);
            a[2*m] = s0; a[2*m+1] = s1;
        }
    }
    #pragma unroll
    for (int m = 0; m < 8; ++m) {
        atomicAdd(out + (size_t)(rg * 8 + m) * CC + n,     a[2*m]);
        atomicAdd(out + (size_t)(rg * 8 + m) * CC + n + 1, a[2*m+1]);
    }
}

extern "C" void kernel_launch(void* const* d_in, const int* in_sizes, int n_in,
                              void* d_out, int out_size, void* d_ws, size_t ws_size,
                              hipStream_t stream)
{
    const float* x   = (const float*)d_in[0];
    const float* ck  = (const float*)d_in[1];
    const float* cv  = (const float*)d_in[2];
    const float* wq  = (const float*)d_in[3];
    const float* wk  = (const float*)d_in[4];
    const float* wv  = (const float*)d_in[5];
    const float* wpj = (const float*)d_in[6];
    const int*   sp  = (const int*)d_in[7];
    char* ws = (char*)d_ws;
    float* qws  = (float*)(ws + Q_OFF);
    float* knew = (float*)(ws + KNEW_OFF);
    float* vnew = (float*)(ws + VNEW_OFF);
    float* yws  = (float*)(ws + Y_OFF);
    float* scr  = (float*)(ws + SCR_OFF);
    float* out  = (float*)d_out;

    // zero the QKV atomic accumulator (64 x 3072 f32 = 0.75 MB)
    hipMemsetAsync(scr, 0, (size_t)64 * 3072 * sizeof(float), stream);

    hipLaunchKernelGGL(k_qkv,  dim3(48, 32),   dim3(256), 0, stream, x, wq, wk, wv, scr);
    hipLaunchKernelGGL(k_fix,  dim3(6, 64),    dim3(256), 0, stream, scr, sp, qws, knew, vnew);
    hipLaunchKernelGGL(k_attn, dim3(64 * NCH), dim3(256), 0, stream, qws, ck, cv, knew, vnew, scr);
    hipLaunchKernelGGL(k_comb, dim3(1024),     dim3(128), 0, stream, scr, yws, out);
    hipLaunchKernelGGL(k_proj, dim3(32, 16),   dim3(256), 0, stream, yws, wpj, out);
}

// Round 8
// 347.227 us; speedup vs baseline: 1.0748x; 1.0748x over previous
//
#include <hip/hip_runtime.h>
#include <math.h>

// Problem constants
#define BB   16
#define TT   4
#define CC   2048
#define NH   16
#define NKV  4
#define DH   128
#define GRP  4
#define SCACHE 4096
#define SATT 2052          // sink(4) + window(2048)
#define CS   128           // keys per attention chunk (32 per wave)
#define NCH  17            // ceil(2052/128)
#define KSPL 32            // K-split for QKV GEMM (slice = 64)
#define KSPL_P 16          // K-split for proj GEMM (slice = 128)

typedef unsigned int  uint32;
typedef unsigned short ushort_t;
typedef __attribute__((ext_vector_type(8))) __bf16 bf16x8;
typedef __attribute__((ext_vector_type(4))) float  f32x4;

__device__ __forceinline__ uint32 f2bf_bits(float f) {
    uint32 u = __float_as_uint(f);
    return (u + 0x7FFFu + ((u >> 16) & 1u)) >> 16;   // RN-even
}
__device__ __forceinline__ uint32 pk2(float lo, float hi) {
    return f2bf_bits(lo) | (f2bf_bits(hi) << 16);
}
// static-index float4 component (folds under #pragma unroll)
#define F4C(v, j) ((j)==0 ? (v).x : (j)==1 ? (v).y : (j)==2 ? (v).z : (v).w)

// ---- Workspace layout (bytes) ----
// scr region holds up to 25.2 MB of QKV partials (KSPL=32); total ~26.5 MB.
// d_ws is >= 512 MiB (poison fill WRITE_SIZE), so ample headroom.
#define Q_OFF    0
#define KNEW_OFF 524288
#define VNEW_OFF 655360
#define Y_OFF    786432
#define SCR_OFF  1310720

// -------- Kernel 1: QKV GEMM, KSPL=32 (slice 64) -------------------------------
// grid (48, 32): x = col-tile of 64, y = k-slice of 64. Weights read once.
// Streaming partial writes (distinct addresses, full BW) — atomics to a small
// accumulator regressed (r7: L2 same-line serialization).
__global__ __launch_bounds__(256) void k_qkv(
    const float* __restrict__ x, const float* __restrict__ wq,
    const float* __restrict__ wk, const float* __restrict__ wv,
    float* __restrict__ part_qkv)
{
    __shared__ float xs[64][64];           // 16 KB
    int ns = blockIdx.x, ks = blockIdx.y;
    int tid = threadIdx.x;
    int k0 = ks * 64;

    #pragma unroll
    for (int it = 0; it < 4; ++it) {
        int slot = it * 256 + tid;          // 1024 float4 slots
        int row = slot >> 4, c4 = slot & 15;
        *(float4*)&xs[row][c4 * 4] = *(const float4*)(x + (size_t)row * CC + k0 + c4 * 4);
    }
    __syncthreads();

    int cp = tid & 31, rg = tid >> 5;       // col pair, row group of 8
    const float* wp; int ldw, col;
    if (ns < 32)      { ldw = 2048; col = ns * 64 + cp * 2;
                        wp = wq + (size_t)k0 * 2048 + ns * 64 + cp * 2; }
    else if (ns < 40) { ldw = 512;  col = 2048 + (ns - 32) * 64 + cp * 2;
                        wp = wk + (size_t)k0 * 512 + (ns - 32) * 64 + cp * 2; }
    else              { ldw = 512;  col = 2560 + (ns - 40) * 64 + cp * 2;
                        wp = wv + (size_t)k0 * 512 + (ns - 40) * 64 + cp * 2; }

    float a[16];
    #pragma unroll
    for (int i = 0; i < 16; ++i) a[i] = 0.f;

    for (int k = 0; k < 64; k += 4) {
        float2 w0 = *(const float2*)(wp);
        float2 w1 = *(const float2*)(wp + ldw);
        float2 w2 = *(const float2*)(wp + 2 * ldw);
        float2 w3 = *(const float2*)(wp + 3 * ldw);
        wp += 4 * ldw;
        #pragma unroll
        for (int m = 0; m < 8; ++m) {
            float4 xv = *(const float4*)&xs[rg * 8 + m][k];
            float s0 = a[2*m], s1 = a[2*m+1];
            s0 = fmaf(xv.x, w0.x, s0); s1 = fmaf(xv.x, w0.y, s1);
            s0 = fmaf(xv.y, w1.x, s0); s1 = fmaf(xv.y, w1.y, s1);
            s0 = fmaf(xv.z, w2.x, s0); s1 = fmaf(xv.z, w2.y, s1);
            s0 = fmaf(xv.w, w3.x, s0); s1 = fmaf(xv.w, w3.y, s1);
            a[2*m] = s0; a[2*m+1] = s1;
        }
    }
    #pragma unroll
    for (int m = 0; m < 8; ++m)
        *(float2*)(part_qkv + ((size_t)(ks * 64 + rg * 8 + m) * 3072) + col) =
            make_float2(a[2*m], a[2*m+1]);
}

// -------- Kernel 2: combine K-split partials + RoPE (KSPL=32) ------------------
__global__ __launch_bounds__(256) void k_fix(
    const float* __restrict__ part_qkv, const int* __restrict__ spp,
    float* __restrict__ qws, float* __restrict__ knew, float* __restrict__ vnew)
{
    int u = blockIdx.x * 256 + threadIdx.x;
    int m = blockIdx.y;
    int b = m >> 2, t = m & 3;
    int sp = spp[0];
    const float NEG_L2_10K_64 = -0.20762050593048633f;

    if (u < 1024) {
        int h = u >> 6, d = u & 63;
        int col = h * 128 + d;
        float s1 = 0.f, s2 = 0.f;
        #pragma unroll
        for (int ks = 0; ks < KSPL; ++ks) {
            const float* p = part_qkv + (size_t)(ks * 64 + m) * 3072;
            s1 += p[col]; s2 += p[col + 64];
        }
        float inv = exp2f((float)d * NEG_L2_10K_64);
        float ang = (float)(sp + t) * inv;
        float cc = cosf(ang), ss = sinf(ang);
        float* dst = qws + (size_t)((b * NH + h) * TT + t) * DH + d;
        dst[0]  = s1 * cc - s2 * ss;
        dst[64] = s1 * ss + s2 * cc;
    } else if (u < 1280) {
        int v = u - 1024;
        int kv = v >> 6, d = v & 63;
        int col = 2048 + kv * 128 + d;
        float s1 = 0.f, s2 = 0.f;
        #pragma unroll
        for (int ks = 0; ks < KSPL; ++ks) {
            const float* p = part_qkv + (size_t)(ks * 64 + m) * 3072;
            s1 += p[col]; s2 += p[col + 64];
        }
        float inv = exp2f((float)d * NEG_L2_10K_64);
        float ang = (float)(sp + t) * inv;
        float cc = cosf(ang), ss = sinf(ang);
        float* dst = knew + (size_t)((b * NKV + kv) * TT + t) * DH + d;
        dst[0]  = s1 * cc - s2 * ss;
        dst[64] = s1 * ss + s2 * cc;
    } else {
        int v = u - 1280;
        int c0 = v * 2;
        int kv = c0 >> 7, dd = c0 & 127;
        float s1 = 0.f, s2 = 0.f;
        #pragma unroll
        for (int ks = 0; ks < KSPL; ++ks) {
            const float* p = part_qkv + (size_t)(ks * 64 + m) * 3072 + 2560 + c0;
            s1 += p[0]; s2 += p[1];
        }
        float* dst = vnew + (size_t)((b * NKV + kv) * TT + t) * DH + dd;
        dst[0] = s1; dst[1] = s2;
    }
}

// key/value row j in [0, 2052)
__device__ __forceinline__ const float* kv_row(
    const float* cache, const float* newt, int bk, int j)
{
    if (j < 4)         return cache + ((size_t)bk * SCACHE + j) * DH;
    else if (j < 2048) return cache + ((size_t)bk * SCACHE + j + 2048) * DH;
    else               return newt  + ((size_t)(bk * TT + (j - 2048))) * DH;
}

// -------- Kernel 3: MFMA flash-decode attention partials -----------------------
// Round-6 structure (CS=128, 1088 blocks = 4.25 blk/CU). ONLY delta vs r6:
// s_setprio(1/0) around the two MFMA clusters (T5 isolate — independent wave
// chains = the m191 regime where setprio paid; r7's bundle masked its effect).
// Verified layouts: A[m=lane&15][k=quad*8+j], B[k=quad*8+j][n=lane&15],
// C/D[row=quad*4+reg][col=lane&15].
__global__ __launch_bounds__(256) void k_attn(
    const float* __restrict__ qws,
    const float* __restrict__ kc, const float* __restrict__ vc,
    const float* __restrict__ knew, const float* __restrict__ vnew,
    float* __restrict__ part)
{
    // words: [0,8192) vt (4 waves x 2048w) -- phase2: o_all [4][16][132] f32 (8448w)
    //        [8448,9472) pl (4 waves x 256w = [16][32] u16 each)
    //        [9472,9536) red_m[4][16]  [9536,9600) red_l[4][16]
    __shared__ __align__(16) uint32 smem[9600];   // 38400 B

    int bx = blockIdx.x;
    int c  = bx % NCH;
    int bk = bx / NCH;
    int b  = bk >> 2, kvh = bk & 3;
    int j0 = c * CS;
    int jn = (SATT - j0 < CS) ? (SATT - j0) : CS;
    int tid  = threadIdx.x;
    int w    = tid >> 6, lane = tid & 63;
    int quad = lane >> 4, l15 = lane & 15;
    const float scale = 0.08838834764831845f;   // 1/sqrt(128), folded into Q

    uint32*   vt    = smem + w * 2048;                       // [128 d][16 u32] swz
    ushort_t* pl    = (ushort_t*)(smem + 8448) + w * 512;    // [16 r][32 k] u16 swz
    float*    red_m = (float*)(smem + 9472);
    float*    red_l = red_m + 64;
    float*    o_all = (float*)smem;                          // [4][16][132] (phase 2)

    int base = w * 32;                      // wave's first local key

    // ---- K rows (base+l15, base+16+l15), clamped; 128 d each ----
    int rA = base + l15, rB = base + 16 + l15;
    const float* kAp = kv_row(kc, knew, bk, j0 + (rA < jn ? rA : 0));
    const float* kBp = kv_row(kc, knew, bk, j0 + (rB < jn ? rB : 0));
    float4 ka[8], kb[8];
    #pragma unroll
    for (int ks = 0; ks < 4; ++ks) {
        ka[2*ks]   = *(const float4*)(kAp + ks * 32 + quad * 8);
        ka[2*ks+1] = *(const float4*)(kAp + ks * 32 + quad * 8 + 4);
        kb[2*ks]   = *(const float4*)(kBp + ks * 32 + quad * 8);
        kb[2*ks+1] = *(const float4*)(kBp + ks * 32 + quad * 8 + 4);
    }

    // ---- V burst 1: lane = (pair p=l15, d-quarter dq=quad), d [dq*32, +16) ----
    int key0 = base + 2 * l15, key1 = key0 + 1;
    bool okA = key0 < jn, okB = key1 < jn;
    const float* rva = kv_row(vc, vnew, bk, j0 + (okA ? key0 : 0));
    const float* rvb = kv_row(vc, vnew, bk, j0 + (okB ? key1 : 0));
    float4 va[4], vb[4];
    #pragma unroll
    for (int i = 0; i < 4; ++i) {
        va[i] = *(const float4*)(rva + quad * 32 + i * 4);
        vb[i] = *(const float4*)(rvb + quad * 32 + i * 4);
    }

    // ---- Q fragments, scale folded (L2-hot) ----
    bf16x8 aq[4];
    {
        int h = kvh * GRP + (l15 >> 2), t = l15 & 3;
        const float* qr = qws + (size_t)((b * NH + h) * TT + t) * DH;
        #pragma unroll
        for (int ks = 0; ks < 4; ++ks) {
            float4 f0 = *(const float4*)(qr + ks * 32 + quad * 8);
            float4 f1 = *(const float4*)(qr + ks * 32 + quad * 8 + 4);
            union { uint32 u[4]; bf16x8 v; } pk_;
            pk_.u[0] = pk2(f0.x * scale, f0.y * scale);
            pk_.u[1] = pk2(f0.z * scale, f0.w * scale);
            pk_.u[2] = pk2(f1.x * scale, f1.y * scale);
            pk_.u[3] = pk2(f1.z * scale, f1.w * scale);
            aq[ks] = pk_.v;
        }
    }

    // ---- QK^T: 8 MFMAs (2 key-tiles x 4 ks) ----
    f32x4 s0 = {0.f, 0.f, 0.f, 0.f}, s1 = {0.f, 0.f, 0.f, 0.f};
    __builtin_amdgcn_s_setprio(1);
    #pragma unroll
    for (int ks = 0; ks < 4; ++ks) {
        union { uint32 u[4]; bf16x8 v; } pa, pb;
        pa.u[0] = pk2(ka[2*ks].x,   ka[2*ks].y);
        pa.u[1] = pk2(ka[2*ks].z,   ka[2*ks].w);
        pa.u[2] = pk2(ka[2*ks+1].x, ka[2*ks+1].y);
        pa.u[3] = pk2(ka[2*ks+1].z, ka[2*ks+1].w);
        pb.u[0] = pk2(kb[2*ks].x,   kb[2*ks].y);
        pb.u[1] = pk2(kb[2*ks].z,   kb[2*ks].w);
        pb.u[2] = pk2(kb[2*ks+1].x, kb[2*ks+1].y);
        pb.u[3] = pk2(kb[2*ks+1].z, kb[2*ks+1].w);
        s0 = __builtin_amdgcn_mfma_f32_16x16x32_bf16(aq[ks], pa.v, s0, 0, 0, 0);
        s1 = __builtin_amdgcn_mfma_f32_16x16x32_bf16(aq[ks], pb.v, s1, 0, 0, 0);
    }
    __builtin_amdgcn_s_setprio(0);

    // ---- stage V burst1 -> vt (swizzled); issue burst2 ----
    #pragma unroll
    for (int i = 0; i < 4; ++i) {
        #pragma unroll
        for (int jj = 0; jj < 4; ++jj) {
            int dd = i * 4 + jj;                       // 0..15 (compile-time)
            int d  = quad * 32 + dd;
            int sw = (dd ^ (dd >> 2)) & 3;             // compile-time
            float fa = okA ? F4C(va[i], jj) : 0.f;
            float fb = okB ? F4C(vb[i], jj) : 0.f;
            vt[d * 16 + ((((l15 >> 2) ^ sw) << 2) | (l15 & 3))] = pk2(fa, fb);
        }
    }
    float4 va2[4], vb2[4];
    #pragma unroll
    for (int i = 0; i < 4; ++i) {
        va2[i] = *(const float4*)(rva + quad * 32 + 16 + i * 4);
        vb2[i] = *(const float4*)(rvb + quad * 32 + 16 + i * 4);
    }

    // ---- per-wave softmax over its 32 keys (no cross-wave traffic) ----
    bool c0ok = (base + l15) < jn, c1ok = (base + 16 + l15) < jn;
    float sc0[4], sc1[4], mloc[4];
    #pragma unroll
    for (int i = 0; i < 4; ++i) {
        sc0[i] = c0ok ? s0[i] : -1e30f;
        sc1[i] = c1ok ? s1[i] : -1e30f;
        float v = fmaxf(sc0[i], sc1[i]);
        v = fmaxf(v, __shfl_xor(v, 1));
        v = fmaxf(v, __shfl_xor(v, 2));
        v = fmaxf(v, __shfl_xor(v, 4));
        v = fmaxf(v, __shfl_xor(v, 8));
        mloc[i] = v;
        float p0 = __expf(sc0[i] - v);     // all-masked wave: exp(0)=1, killed later
        float p1 = __expf(sc1[i] - v);
        int r   = quad * 4 + i;
        int swr = (i ^ quad) & 3;          // (r ^ (r>>2)) & 3
        pl[r * 32 + ((((l15 >> 3)    ) ^ swr) << 3) + (l15 & 7)] = (ushort_t)f2bf_bits(p0);
        pl[r * 32 + ((((l15 >> 3) | 2) ^ swr) << 3) + (l15 & 7)] = (ushort_t)f2bf_bits(p1);
        float su = p0 + p1;
        su += __shfl_xor(su, 1);
        su += __shfl_xor(su, 2);
        su += __shfl_xor(su, 4);
        su += __shfl_xor(su, 8);
        if (l15 == 0) { red_m[w * 16 + r] = v; red_l[w * 16 + r] = su; }
    }

    // ---- stage V burst2 ----
    #pragma unroll
    for (int i = 0; i < 4; ++i) {
        #pragma unroll
        for (int jj = 0; jj < 4; ++jj) {
            int dd = 16 + i * 4 + jj;                  // 16..31 (compile-time)
            int d  = quad * 32 + dd;
            int sw = (dd ^ (dd >> 2)) & 3;
            float fa = okA ? F4C(va2[i], jj) : 0.f;
            float fb = okB ? F4C(vb2[i], jj) : 0.f;
            vt[d * 16 + ((((l15 >> 2) ^ sw) << 2) | (l15 & 3))] = pk2(fa, fb);
        }
    }

    // ---- PV: one k=32 MFMA per 16-d tile (8 total); wave-private LDS reads ----
    int swp = (l15 ^ (l15 >> 2)) & 3;
    bf16x8 ap = *(const bf16x8*)&pl[l15 * 32 + ((quad ^ swp) << 3)];
    f32x4 o[8];
    #pragma unroll
    for (int t = 0; t < 8; ++t) o[t] = (f32x4){0.f, 0.f, 0.f, 0.f};
    __builtin_amdgcn_s_setprio(1);
    #pragma unroll
    for (int t = 0; t < 8; ++t) {
        int d   = t * 16 + l15;
        int swv = (d ^ (d >> 2)) & 3;
        bf16x8 bv = *(const bf16x8*)&vt[d * 16 + ((quad ^ swv) << 2)];
        o[t] = __builtin_amdgcn_mfma_f32_16x16x32_bf16(ap, bv, o[t], 0, 0, 0);
    }
    __builtin_amdgcn_s_setprio(0);

    // ---- tail merge: rescale to block max, sum 4 waves in LDS ----
    __syncthreads();    // all PV LDS reads + red_m/red_l writes done
    #pragma unroll
    for (int i = 0; i < 4; ++i) {
        int r = quad * 4 + i;
        float Mb = fmaxf(fmaxf(red_m[r], red_m[16 + r]),
                         fmaxf(red_m[32 + r], red_m[48 + r]));
        float scl = __expf(mloc[i] - Mb);   // fully-masked wave -> 0
        #pragma unroll
        for (int t = 0; t < 8; ++t)
            o_all[(w * 16 + r) * 132 + t * 16 + l15] = o[t][i] * scl;
    }
    __syncthreads();
    {
        int r = tid >> 4, dg = tid & 15;    // 16 rows x 16 d-groups of 8
        float acc[8];
        #pragma unroll
        for (int jj = 0; jj < 8; ++jj) acc[jj] = 0.f;
        #pragma unroll
        for (int ww = 0; ww < 4; ++ww) {
            const float* src = &o_all[(ww * 16 + r) * 132 + dg * 8];
            #pragma unroll
            for (int jj = 0; jj < 8; ++jj) acc[jj] += src[jj];
        }
        float* dstb = part + (size_t)(bk * NCH + c) * 16 * 132;
        #pragma unroll
        for (int jj = 0; jj < 8; ++jj) dstb[r * 132 + 4 + dg * 8 + jj] = acc[jj];
        if (dg == 0) {
            float Mb = fmaxf(fmaxf(red_m[r], red_m[16 + r]),
                             fmaxf(red_m[32 + r], red_m[48 + r]));
            float L = 0.f;
            #pragma unroll
            for (int ww = 0; ww < 4; ++ww)
                L += __expf(red_m[ww * 16 + r] - Mb) * red_l[ww * 16 + r];
            dstb[r * 132 + 0] = Mb;
            dstb[r * 132 + 1] = L;
        }
    }
}

// -------- Kernel 4: combine chunk partials -> yws; zero proj accumulator -------
__global__ __launch_bounds__(128) void k_comb(
    const float* __restrict__ part, float* __restrict__ yws,
    float* __restrict__ out)
{
    int bx = blockIdx.x;
    // zero the projection output accumulator (1024 blk x 128 thr = 131072 = 64*2048)
    out[(size_t)bx * 128 + threadIdx.x] = 0.f;

    int t = bx & 3, h = (bx >> 2) & 15, b = bx >> 6;
    int bk = b * NKV + (h >> 2);
    int r  = (h & 3) * 4 + t;
    int d  = threadIdx.x;
    float M = -1e30f;
    for (int c = 0; c < NCH; ++c)
        M = fmaxf(M, part[((size_t)(bk * NCH + c) * 16 + r) * 132]);
    float L = 0.f, y = 0.f;
    for (int c = 0; c < NCH; ++c) {
        const float* pp = part + ((size_t)(bk * NCH + c) * 16 + r) * 132;
        float w = __expf(pp[0] - M);
        L += w * pp[1];
        y  = fmaf(w, pp[4 + d], y);
    }
    yws[(size_t)(b * TT + t) * CC + h * DH + d] = y / L;
}

// -------- Kernel 5: output projection GEMM, KSPL_P=16, atomicAdd into out ------
// grid (32, 16): x = col-tile of 64, y = k-slice of 128.
__global__ __launch_bounds__(256) void k_proj(
    const float* __restrict__ yws, const float* __restrict__ wp,
    float* __restrict__ out)
{
    __shared__ float xs[64][128];          // 32 KB
    int ns = blockIdx.x, ks = blockIdx.y;
    int tid = threadIdx.x;
    int k0 = ks * 128;
    #pragma unroll
    for (int it = 0; it < 8; ++it) {
        int slot = it * 256 + tid;          // 2048 float4 slots
        int row = slot >> 5, c4 = slot & 31;
        *(float4*)&xs[row][c4 * 4] = *(const float4*)(yws + (size_t)row * CC + k0 + c4 * 4);
    }
    __syncthreads();

    int cp = tid & 31, rg = tid >> 5;
    int n = ns * 64 + cp * 2;
    const float* w = wp + (size_t)k0 * CC + n;
    float a[16];
    #pragma unroll
    for (int i = 0; i < 16; ++i) a[i] = 0.f;

    for (int k = 0; k < 128; k += 4) {
        float2 w0 = *(const float2*)(w);
        float2 w1 = *(const float2*)(w + CC);
        float2 w2 = *(const float2*)(w + 2 * CC);
        float2 w3 = *(const float2*)(w + 3 * CC);
        w += 4 * CC;
        #pragma unroll
        for (int m = 0; m < 8; ++m) {
            float4 xv = *(const float4*)&xs[rg * 8 + m][k];
            float s0 = a[2*m], s1 = a[2*m+1];
            s0 = fmaf(xv.x, w0.x, s0); s1 = fmaf(xv.x, w0.y, s1);
            s0 = fmaf(xv.y, w1.x, s0); s1 = fmaf(xv.y, w1.y, s1);
            s0 = fmaf(xv.z, w2.x, s0); s1 = fmaf(xv.z, w2.y, s1);
            s0 = fmaf(xv.w, w3.x, s0); s1 = fmaf(xv.w, w3.y, s1);
            a[2*m] = s0; a[2*m+1] = s1;
        }
    }
    #pragma unroll
    for (int m = 0; m < 8; ++m) {
        atomicAdd(out + (size_t)(rg * 8 + m) * CC + n,     a[2*m]);
        atomicAdd(out + (size_t)(rg * 8 + m) * CC + n + 1, a[2*m+1]);
    }
}

extern "C" void kernel_launch(void* const* d_in, const int* in_sizes, int n_in,
                              void* d_out, int out_size, void* d_ws, size_t ws_size,
                              hipStream_t stream)
{
    const float* x   = (const float*)d_in[0];
    const float* ck  = (const float*)d_in[1];
    const float* cv  = (const float*)d_in[2];
    const float* wq  = (const float*)d_in[3];
    const float* wk  = (const float*)d_in[4];
    const float* wv  = (const float*)d_in[5];
    const float* wpj = (const float*)d_in[6];
    const int*   sp  = (const int*)d_in[7];
    char* ws = (char*)d_ws;
    float* qws  = (float*)(ws + Q_OFF);
    float* knew = (float*)(ws + KNEW_OFF);
    float* vnew = (float*)(ws + VNEW_OFF);
    float* yws  = (float*)(ws + Y_OFF);
    float* scr  = (float*)(ws + SCR_OFF);
    float* out  = (float*)d_out;

    hipLaunchKernelGGL(k_qkv,  dim3(48, 32),   dim3(256), 0, stream, x, wq, wk, wv, scr);
    hipLaunchKernelGGL(k_fix,  dim3(6, 64),    dim3(256), 0, stream, scr, sp, qws, knew, vnew);
    hipLaunchKernelGGL(k_attn, dim3(64 * NCH), dim3(256), 0, stream, qws, ck, cv, knew, vnew, scr);
    hipLaunchKernelGGL(k_comb, dim3(1024),     dim3(128), 0, stream, scr, yws, out);
    hipLaunchKernelGGL(k_proj, dim3(32, 16),   dim3(256), 0, stream, yws, wpj, out);
}